// Round 1
// baseline (454.445 us; speedup 1.0000x reference)
//
#include <hip/hip_runtime.h>
#include <hip/hip_bf16.h>
#include <stdint.h>

// ---------------------------------------------------------------------------
// MultiHeadAttention on MI355X (gfx950).
// b=2, n=1024, DIM=1024, H=16, dh=64.  Outputs: out (2M f32) ++ attn (33.5M f32).
// All GEMMs use bf16 MFMA 16x16x32 with hi/lo split (3 MFMAs) => ~fp32 accuracy.
// ---------------------------------------------------------------------------

#define NB   2
#define SEQ  1024
#define CDIM 1024
#define NH   16
#define HD   64
#define ROWS (NB*SEQ)          // 2048
#define ATT_SCALE 0.125f       // 64^-0.5

typedef __attribute__((ext_vector_type(8))) short bf16x8;
typedef __attribute__((ext_vector_type(4))) float f32x4;

#define MFMA16(a,b,c) __builtin_amdgcn_mfma_f32_16x16x32_bf16((a),(b),(c),0,0,0)

static __device__ __forceinline__ unsigned short f2bf(float f) {
  uint32_t x = __builtin_bit_cast(uint32_t, f);
  return (unsigned short)((x + 0x7fffu + ((x >> 16) & 1u)) >> 16);   // RTN-even
}
static __device__ __forceinline__ float bf2f(unsigned short u) {
  uint32_t x = ((uint32_t)u) << 16;
  return __builtin_bit_cast(float, x);
}

// ---------------------------------------------------------------------------
// K0: fp32 -> bf16 hi/lo split for x and concatenated W = [Wq; Wkv; Wp] (4096x1024)
// ---------------------------------------------------------------------------
__global__ __launch_bounds__(256) void k_convert(
    const float* __restrict__ x, const float* __restrict__ Wq,
    const float* __restrict__ Wkv, const float* __restrict__ Wp,
    unsigned short* __restrict__ Xhi, unsigned short* __restrict__ Xlo,
    unsigned short* __restrict__ Whi, unsigned short* __restrict__ Wlo)
{
  const int NX = ROWS * CDIM;        // 2,097,152
  const int NW = 4096 * CDIM;        // 4,194,304
  int i = blockIdx.x * 256 + threadIdx.x;
  if (i < NX) {
    float f = x[i];
    unsigned short h = f2bf(f);
    Xhi[i] = h; Xlo[i] = f2bf(f - bf2f(h));
  } else if (i < NX + NW) {
    int w = i - NX;
    int j = w >> 10, c = w & 1023;
    float f = (j < 1024) ? Wq[(size_t)j*1024 + c]
            : (j < 3072) ? Wkv[(size_t)(j-1024)*1024 + c]
                         : Wp[(size_t)(j-3072)*1024 + c];
    unsigned short h = f2bf(f);
    Whi[w] = h; Wlo[w] = f2bf(f - bf2f(h));
  }
}

// ---------------------------------------------------------------------------
// Shared 128x128 NT-GEMM core (split bf16, BK=32, 256 threads = 2x2 waves of 64x64)
// C[m][n] = sum_k A[m][k]*B[n][k]    (A,B row-major, k contiguous)
// ---------------------------------------------------------------------------
struct EpiQKV {
  const float* bq; const float* bkv;
  unsigned short *Qhi, *Qlo, *Khi, *Klo, *Vthi, *Vtlo;
  __device__ __forceinline__ void operator()(int m, int n, float v) const {
    if (n < 1024) {                       // Q
      v += bq[n];
      unsigned short h = f2bf(v);
      size_t o = (size_t)m*1024 + n;
      Qhi[o] = h; Qlo[o] = f2bf(v - bf2f(h));
    } else if (n < 2048) {                // K
      v += bkv[n - 1024];
      size_t o = (size_t)m*1024 + (n - 1024);
      unsigned short h = f2bf(v);
      Khi[o] = h; Klo[o] = f2bf(v - bf2f(h));
    } else {                              // V -> transposed [b][h][d][m]
      v += bkv[n - 1024];
      int c = n - 2048;
      int hh = c >> 6, d = c & 63;
      int b = m >> 10, mm = m & 1023;
      size_t o = ((size_t)((b*NH + hh)*HD + d))*SEQ + mm;
      unsigned short h = f2bf(v);
      Vthi[o] = h; Vtlo[o] = f2bf(v - bf2f(h));
    }
  }
};
struct EpiOut {
  const float* bp; float* out;
  __device__ __forceinline__ void operator()(int m, int n, float v) const {
    out[(size_t)m*1024 + n] = v + bp[n];
  }
};

template <class Epi>
__device__ __forceinline__ void gemm128_core(
    const unsigned short* __restrict__ Ahi, const unsigned short* __restrict__ Alo, int lda,
    const unsigned short* __restrict__ Bhi, const unsigned short* __restrict__ Blo, int ldb,
    int K, const Epi& epi)
{
  __shared__ unsigned short sAh[128*32], sAl[128*32], sBh[128*32], sBl[128*32];
  const int tid  = threadIdx.x;
  const int lane = tid & 63, wave = tid >> 6;
  const int wm = wave & 1, wn = wave >> 1;
  const int bn = blockIdx.x * 128, bm = blockIdx.y * 128;
  const int sk = (tid & 3) * 8;
  const int r = lane & 15, q = lane >> 4;

  f32x4 acc[4][4];
  #pragma unroll
  for (int i = 0; i < 4; i++)
    #pragma unroll
    for (int j = 0; j < 4; j++) {
      acc[i][j][0]=0.f; acc[i][j][1]=0.f; acc[i][j][2]=0.f; acc[i][j][3]=0.f;
    }

  for (int k0 = 0; k0 < K; k0 += 32) {
    #pragma unroll
    for (int half = 0; half < 2; half++) {
      int row = (tid >> 2) + half*64;
      uint4 va = *(const uint4*)(Ahi + (size_t)(bm + row)*lda + k0 + sk);
      uint4 vb = *(const uint4*)(Alo + (size_t)(bm + row)*lda + k0 + sk);
      uint4 vc = *(const uint4*)(Bhi + (size_t)(bn + row)*ldb + k0 + sk);
      uint4 vd = *(const uint4*)(Blo + (size_t)(bn + row)*ldb + k0 + sk);
      *(uint4*)(sAh + row*32 + sk) = va;
      *(uint4*)(sAl + row*32 + sk) = vb;
      *(uint4*)(sBh + row*32 + sk) = vc;
      *(uint4*)(sBl + row*32 + sk) = vd;
    }
    __syncthreads();
    bf16x8 ah[4], al[4], bh[4], bl[4];
    #pragma unroll
    for (int i = 0; i < 4; i++) {
      int oa = (wm*64 + i*16 + r)*32 + q*8;
      int ob = (wn*64 + i*16 + r)*32 + q*8;
      ah[i] = *(const bf16x8*)(sAh + oa);
      al[i] = *(const bf16x8*)(sAl + oa);
      bh[i] = *(const bf16x8*)(sBh + ob);
      bl[i] = *(const bf16x8*)(sBl + ob);
    }
    #pragma unroll
    for (int i = 0; i < 4; i++)
      #pragma unroll
      for (int j = 0; j < 4; j++) {
        acc[i][j] = MFMA16(ah[i], bh[j], acc[i][j]);
        acc[i][j] = MFMA16(ah[i], bl[j], acc[i][j]);
        acc[i][j] = MFMA16(al[i], bh[j], acc[i][j]);
      }
    __syncthreads();
  }
  #pragma unroll
  for (int i = 0; i < 4; i++)
    #pragma unroll
    for (int j = 0; j < 4; j++)
      #pragma unroll
      for (int t = 0; t < 4; t++)
        epi(bm + wm*64 + i*16 + q*4 + t, bn + wn*64 + j*16 + r, acc[i][j][t]);
}

__global__ __launch_bounds__(256) void k_gemm_qkv(
    const unsigned short* Xhi, const unsigned short* Xlo,
    const unsigned short* Whi, const unsigned short* Wlo,
    const float* bq, const float* bkv,
    unsigned short* Qhi, unsigned short* Qlo,
    unsigned short* Khi, unsigned short* Klo,
    unsigned short* Vthi, unsigned short* Vtlo)
{
  EpiQKV e{bq, bkv, Qhi, Qlo, Khi, Klo, Vthi, Vtlo};
  gemm128_core(Xhi, Xlo, CDIM, Whi, Wlo, CDIM, CDIM, e);
}

__global__ __launch_bounds__(256) void k_gemm_out(
    const unsigned short* OAhi, const unsigned short* OAlo,
    const unsigned short* Wphi, const unsigned short* Wplo,
    const float* bp, float* out)
{
  EpiOut e{bp, out};
  gemm128_core(OAhi, OAlo, CDIM, Wphi, Wplo, CDIM, CDIM, e);
}

// ---------------------------------------------------------------------------
// K2: logits = scale * Q K^T, written DIRECTLY in final attn layout [b][n][m][h].
// wg = (b, 16-n-tile, 32-m-tile), 128 threads (2 waves = 2 m-halves), loops 16 heads
// into an LDS slab [16n][32m][pad20] then writes coalesced float4s.
// ---------------------------------------------------------------------------
#define SLAB_PAD 20
__global__ __launch_bounds__(128) void k_logits(
    const unsigned short* __restrict__ Qhi, const unsigned short* __restrict__ Qlo,
    const unsigned short* __restrict__ Khi, const unsigned short* __restrict__ Klo,
    float* __restrict__ attn)
{
  int mt = blockIdx.x, nt = blockIdx.y, b = blockIdx.z;
  int n0 = nt*16, m0 = mt*32;
  __shared__ unsigned short sQh[16*64], sQl[16*64], sKh[32*64], sKl[32*64];
  __shared__ float slab[16*32*SLAB_PAD];
  const int tid = threadIdx.x, lane = tid & 63, wave = tid >> 6;
  const int r = lane & 15, q = lane >> 4;

  for (int h = 0; h < NH; h++) {
    {   // stage Q (16x64) and K (32x64), hi+lo
      int row = tid >> 3, ch = (tid & 7) * 8;
      size_t gq = (size_t)(b*SEQ + n0 + row)*CDIM + h*HD + ch;
      *(uint4*)(sQh + row*64 + ch) = *(const uint4*)(Qhi + gq);
      *(uint4*)(sQl + row*64 + ch) = *(const uint4*)(Qlo + gq);
      #pragma unroll
      for (int it = 0; it < 2; it++) {
        int idx = tid + it*128;
        int krow = idx >> 3, kch = (idx & 7) * 8;
        size_t gk = (size_t)(b*SEQ + m0 + krow)*CDIM + h*HD + kch;
        *(uint4*)(sKh + krow*64 + kch) = *(const uint4*)(Khi + gk);
        *(uint4*)(sKl + krow*64 + kch) = *(const uint4*)(Klo + gk);
      }
    }
    __syncthreads();
    {
      f32x4 acc; acc[0]=0.f; acc[1]=0.f; acc[2]=0.f; acc[3]=0.f;
      #pragma unroll
      for (int ks = 0; ks < 2; ks++) {
        bf16x8 qh = *(const bf16x8*)(sQh + r*64 + ks*32 + q*8);
        bf16x8 ql = *(const bf16x8*)(sQl + r*64 + ks*32 + q*8);
        bf16x8 kh = *(const bf16x8*)(sKh + (wave*16 + r)*64 + ks*32 + q*8);
        bf16x8 kl = *(const bf16x8*)(sKl + (wave*16 + r)*64 + ks*32 + q*8);
        acc = MFMA16(qh, kh, acc);
        acc = MFMA16(qh, kl, acc);
        acc = MFMA16(ql, kh, acc);
      }
      #pragma unroll
      for (int t = 0; t < 4; t++) {
        int nn = q*4 + t;          // D row = n index
        int mm = wave*16 + r;      // D col = m index
        slab[(nn*32 + mm)*SLAB_PAD + h] = acc[t] * ATT_SCALE;
      }
    }
    __syncthreads();
  }
  // write: 16 n-rows x (32m x 16h) dwords = 2048 float4s
  for (int it = 0; it < 16; it++) {
    int idx = it*128 + tid;
    int nn = idx >> 7;            // 128 float4 per n-row
    int rem = idx & 127;
    int flat = rem * 4;           // dword in (m,h)
    int mm = flat >> 4, hh = flat & 15;
    float4 v = *(float4*)&slab[(nn*32 + mm)*SLAB_PAD + hh];
    size_t g = (size_t)(b*SEQ + n0 + nn)*(SEQ*NH) + (size_t)(m0 + mm)*NH + hh;
    *(float4*)(attn + g) = v;
  }
}

// ---------------------------------------------------------------------------
// K3: softmax over m for one (b,n) slab [1024m][16h]; writes normalized attn f32
// back in place, plus unnormalized P as u16 fixed point in [b][h][n][m] layout,
// plus scale_pv = 1/(65535*sum).
// ---------------------------------------------------------------------------
__global__ __launch_bounds__(256) void k_softmax(
    float* __restrict__ attn, unsigned short* __restrict__ P,
    float* __restrict__ scale_pv)
{
  int n = blockIdx.x, b = blockIdx.y;
  __shared__ float slab[SEQ*NH];
  __shared__ float red[256];
  __shared__ float gmax[16], ginv[16];
  const int tid = threadIdx.x;
  const size_t base = (size_t)(b*SEQ + n) * (SEQ*NH);

  for (int it = 0; it < 16; it++) {
    int f4 = it*256 + tid;
    *(float4*)&slab[f4*4] = *(const float4*)(attn + base + (size_t)f4*4);
  }
  __syncthreads();
  const int h = tid & 15, mq = tid >> 4;
  float mx = -1e30f;
  for (int i = 0; i < 64; i++) mx = fmaxf(mx, slab[(mq*64 + i)*16 + h]);
  red[tid] = mx;
  __syncthreads();
  if (tid < 16) {
    float m2 = red[tid];
    for (int j = 1; j < 16; j++) m2 = fmaxf(m2, red[j*16 + tid]);
    gmax[tid] = m2;
  }
  __syncthreads();
  float gm = gmax[h];
  float s = 0.f;
  for (int i = 0; i < 64; i++) {
    int idx = (mq*64 + i)*16 + h;
    float p = __expf(slab[idx] - gm);
    slab[idx] = p;
    s += p;
  }
  red[tid] = s;
  __syncthreads();
  if (tid < 16) {
    float s2 = 0.f;
    for (int j = 0; j < 16; j++) s2 += red[j*16 + tid];
    float inv = 1.0f / s2;
    ginv[tid] = inv;
    scale_pv[(size_t)(b*SEQ + n)*NH + tid] = inv * (1.0f/65535.0f);
  }
  __syncthreads();
  // normalized attn out (coalesced)
  for (int it = 0; it < 16; it++) {
    int f4 = it*256 + tid;
    int flat = f4*4;
    int hh = flat & 15;
    float4 v = *(float4*)&slab[flat];
    float4 iv = *(float4*)&ginv[hh];
    v.x *= iv.x; v.y *= iv.y; v.z *= iv.z; v.w *= iv.w;
    *(float4*)(attn + base + (size_t)flat) = v;
  }
  // u16 P in [b][h][n][m]
  int h2 = tid >> 4, l16 = tid & 15;
  size_t pbase = ((size_t)((b*NH + h2)*SEQ + n))*SEQ;
  for (int i = 0; i < 64; i++) {
    int m = i*16 + l16;
    float p = slab[m*16 + h2];
    unsigned int u = (unsigned int)(p * 65535.0f + 0.5f);
    P[pbase + m] = (unsigned short)u;
  }
}

// ---------------------------------------------------------------------------
// K4: PV gemm per (b,h):  OA[n][d] = scale_pv * sum_m P_u16[n][m] * V[m][d]
// P u16 split exactly into two bf16 planes during LDS staging; V from Vt hi/lo.
// wg = 128 n x 64 d; 256 threads.
// ---------------------------------------------------------------------------
__global__ __launch_bounds__(256) void k_pv(
    const unsigned short* __restrict__ P,
    const unsigned short* __restrict__ Vthi, const unsigned short* __restrict__ Vtlo,
    const float* __restrict__ scale_pv,
    unsigned short* __restrict__ OAhi, unsigned short* __restrict__ OAlo)
{
  int nt = blockIdx.x, h = blockIdx.y, b = blockIdx.z;
  int n0 = nt * 128;
  __shared__ unsigned short sPa[128*32], sPb[128*32], sVh[64*32], sVl[64*32];
  const int tid = threadIdx.x, lane = tid & 63, wave = tid >> 6;
  const int r = lane & 15, q = lane >> 4;
  const size_t pbase = ((size_t)(b*NH + h))*SEQ*SEQ;
  const size_t vbase = ((size_t)(b*NH + h))*HD*SEQ;

  f32x4 acc[2][4];
  #pragma unroll
  for (int i = 0; i < 2; i++)
    #pragma unroll
    for (int j = 0; j < 4; j++) {
      acc[i][j][0]=0.f; acc[i][j][1]=0.f; acc[i][j][2]=0.f; acc[i][j][3]=0.f;
    }

  for (int k0 = 0; k0 < SEQ; k0 += 32) {
    #pragma unroll
    for (int c0 = 0; c0 < 2; c0++) {          // P: 128x32 u16 -> two bf16 planes
      int c = tid + c0*256;
      int row = c >> 2, ch = (c & 3) * 8;
      uint4 v = *(const uint4*)(P + pbase + (size_t)(n0 + row)*SEQ + k0 + ch);
      unsigned int wds[4] = {v.x, v.y, v.z, v.w};
      unsigned int pa[4], pb[4];
      #pragma unroll
      for (int e = 0; e < 4; e++) {
        unsigned int lo16 = wds[e] & 0xFFFFu;
        unsigned int hi16 = wds[e] >> 16;
        unsigned int a0 = __builtin_bit_cast(uint32_t, (float)(lo16 & 0xFF00u)) >> 16;
        unsigned int b0 = __builtin_bit_cast(uint32_t, (float)(lo16 & 0x00FFu)) >> 16;
        unsigned int a1 = __builtin_bit_cast(uint32_t, (float)(hi16 & 0xFF00u)) >> 16;
        unsigned int b1 = __builtin_bit_cast(uint32_t, (float)(hi16 & 0x00FFu)) >> 16;
        pa[e] = a0 | (a1 << 16);
        pb[e] = b0 | (b1 << 16);
      }
      *(uint4*)(sPa + row*32 + ch) = make_uint4(pa[0],pa[1],pa[2],pa[3]);
      *(uint4*)(sPb + row*32 + ch) = make_uint4(pb[0],pb[1],pb[2],pb[3]);
    }
    {   // V: 64x32 hi/lo
      int row = tid >> 2, ch = (tid & 3) * 8;
      size_t g = vbase + (size_t)row*SEQ + k0 + ch;
      *(uint4*)(sVh + row*32 + ch) = *(const uint4*)(Vthi + g);
      *(uint4*)(sVl + row*32 + ch) = *(const uint4*)(Vtlo + g);
    }
    __syncthreads();
    bf16x8 pa[2], pb[2];
    #pragma unroll
    for (int i = 0; i < 2; i++) {
      int off = (wave*32 + i*16 + r)*32 + q*8;
      pa[i] = *(const bf16x8*)(sPa + off);
      pb[i] = *(const bf16x8*)(sPb + off);
    }
    #pragma unroll
    for (int j = 0; j < 4; j++) {
      int off = (j*16 + r)*32 + q*8;
      bf16x8 vh = *(const bf16x8*)(sVh + off);
      bf16x8 vl = *(const bf16x8*)(sVl + off);
      #pragma unroll
      for (int i = 0; i < 2; i++) {
        acc[i][j] = MFMA16(pa[i], vh, acc[i][j]);
        acc[i][j] = MFMA16(pb[i], vh, acc[i][j]);
        acc[i][j] = MFMA16(pa[i], vl, acc[i][j]);
      }
    }
    __syncthreads();
  }
  #pragma unroll
  for (int i = 0; i < 2; i++)
    #pragma unroll
    for (int t = 0; t < 4; t++) {
      int nn = n0 + wave*32 + i*16 + q*4 + t;
      float sc = scale_pv[(size_t)(b*SEQ + nn)*NH + h];
      #pragma unroll
      for (int j = 0; j < 4; j++) {
        int d = j*16 + r;
        float val = acc[i][j][t] * sc;
        size_t o = (size_t)(b*SEQ + nn)*CDIM + h*HD + d;
        unsigned short hb = f2bf(val);
        OAhi[o] = hb; OAlo[o] = f2bf(val - bf2f(hb));
      }
    }
}

// ---------------------------------------------------------------------------
extern "C" void kernel_launch(void* const* d_in, const int* in_sizes, int n_in,
                              void* d_out, int out_size, void* d_ws, size_t ws_size,
                              hipStream_t stream)
{
  const float* x   = (const float*)d_in[0];
  const float* Wq  = (const float*)d_in[1];
  const float* bq  = (const float*)d_in[2];
  const float* Wkv = (const float*)d_in[3];
  const float* bkv = (const float*)d_in[4];
  const float* Wp  = (const float*)d_in[5];
  const float* bp  = (const float*)d_in[6];

  float* out  = (float*)d_out;                       // 2048*1024
  float* attn = out + (size_t)ROWS*CDIM;             // 2*1024*1024*16

  char* w = (char*)d_ws;
  unsigned short* Xhi  = (unsigned short*)w; w += (size_t)ROWS*CDIM*2;
  unsigned short* Xlo  = (unsigned short*)w; w += (size_t)ROWS*CDIM*2;
  unsigned short* Whi  = (unsigned short*)w; w += (size_t)4096*CDIM*2;
  unsigned short* Wlo  = (unsigned short*)w; w += (size_t)4096*CDIM*2;
  unsigned short* Qhi  = (unsigned short*)w; w += (size_t)ROWS*CDIM*2;
  unsigned short* Qlo  = (unsigned short*)w; w += (size_t)ROWS*CDIM*2;
  unsigned short* Khi  = (unsigned short*)w; w += (size_t)ROWS*CDIM*2;
  unsigned short* Klo  = (unsigned short*)w; w += (size_t)ROWS*CDIM*2;
  unsigned short* Vthi = (unsigned short*)w; w += (size_t)NB*NH*HD*SEQ*2;
  unsigned short* Vtlo = (unsigned short*)w; w += (size_t)NB*NH*HD*SEQ*2;
  unsigned short* OAhi = (unsigned short*)w; w += (size_t)ROWS*CDIM*2;
  unsigned short* OAlo = (unsigned short*)w; w += (size_t)ROWS*CDIM*2;
  float* scale_pv      = (float*)w;          w += (size_t)NB*SEQ*NH*4;
  unsigned short* P    = (unsigned short*)w; w += (size_t)NB*NH*SEQ*SEQ*2;

  // K0: convert x and W to split bf16
  k_convert<<<dim3((ROWS*CDIM + 4096*CDIM)/256), 256, 0, stream>>>(
      x, Wq, Wkv, Wp, Xhi, Xlo, Whi, Wlo);

  // K1: QKV projection  (2048 x 3072 x 1024)
  k_gemm_qkv<<<dim3(3072/128, 2048/128), 256, 0, stream>>>(
      Xhi, Xlo, Whi, Wlo, bq, bkv, Qhi, Qlo, Khi, Klo, Vthi, Vtlo);

  // K2: logits into d_out attn region, final [b][n][m][h] layout
  k_logits<<<dim3(SEQ/32, SEQ/16, NB), 128, 0, stream>>>(Qhi, Qlo, Khi, Klo, attn);

  // K3: softmax per (b,n); writes normalized attn + u16 P + scales
  k_softmax<<<dim3(SEQ, NB), 256, 0, stream>>>(attn, P, scale_pv);

  // K4: PV per (b,h)
  k_pv<<<dim3(SEQ/128, NH, NB), 256, 0, stream>>>(P, Vthi, Vtlo, scale_pv, OAhi, OAlo);

  // K5: output projection (2048 x 1024 x 1024)
  k_gemm_out<<<dim3(1024/128, 2048/128), 256, 0, stream>>>(
      OAhi, OAlo, Whi + (size_t)3072*CDIM, Wlo + (size_t)3072*CDIM, bp, out);
}

// Round 2
// 421.942 us; speedup vs baseline: 1.0770x; 1.0770x over previous
//
#include <hip/hip_runtime.h>
#include <hip/hip_bf16.h>
#include <stdint.h>

// ---------------------------------------------------------------------------
// MultiHeadAttention on MI355X (gfx950).
// b=2, n=1024, DIM=1024, H=16, dh=64.  Outputs: out (2M f32) ++ attn (33.5M f32).
// All GEMMs: bf16 MFMA 16x16x32, hi/lo split (3 MFMAs) => ~fp32 accuracy.
// R2: global_load_lds (16B DMA) staging everywhere; K5 64x64 (512 blk);
//     K4 64nx64d (512 blk).
// ---------------------------------------------------------------------------

#define NB   2
#define SEQ  1024
#define CDIM 1024
#define NH   16
#define HD   64
#define ROWS (NB*SEQ)          // 2048
#define ATT_SCALE 0.125f       // 64^-0.5

typedef __attribute__((ext_vector_type(8))) short bf16x8;
typedef __attribute__((ext_vector_type(4))) float f32x4;

#define MFMA16(a,b,c) __builtin_amdgcn_mfma_f32_16x16x32_bf16((a),(b),(c),0,0,0)

static __device__ __forceinline__ unsigned short f2bf(float f) {
  uint32_t x = __builtin_bit_cast(uint32_t, f);
  return (unsigned short)((x + 0x7fffu + ((x >> 16) & 1u)) >> 16);   // RTN-even
}
static __device__ __forceinline__ float bf2f(unsigned short u) {
  uint32_t x = ((uint32_t)u) << 16;
  return __builtin_bit_cast(float, x);
}

// async global->LDS DMA, 16B/lane; lds dest = wave-uniform base + lane*16
static __device__ __forceinline__ void gl_lds16(const unsigned short* g,
                                                unsigned short* l) {
  __builtin_amdgcn_global_load_lds(
      (const __attribute__((address_space(1))) unsigned int*)g,
      (__attribute__((address_space(3))) unsigned int*)l,
      16, 0, 0);
}

// ---------------------------------------------------------------------------
// K0: fp32 -> bf16 hi/lo split for x and concatenated W = [Wq; Wkv; Wp]
// ---------------------------------------------------------------------------
__global__ __launch_bounds__(256) void k_convert(
    const float* __restrict__ x, const float* __restrict__ Wq,
    const float* __restrict__ Wkv, const float* __restrict__ Wp,
    unsigned short* __restrict__ Xhi, unsigned short* __restrict__ Xlo,
    unsigned short* __restrict__ Whi, unsigned short* __restrict__ Wlo)
{
  const int NX = ROWS * CDIM;
  const int NW = 4096 * CDIM;
  int i = blockIdx.x * 256 + threadIdx.x;
  if (i < NX) {
    float f = x[i];
    unsigned short h = f2bf(f);
    Xhi[i] = h; Xlo[i] = f2bf(f - bf2f(h));
  } else if (i < NX + NW) {
    int w = i - NX;
    int j = w >> 10, c = w & 1023;
    float f = (j < 1024) ? Wq[(size_t)j*1024 + c]
            : (j < 3072) ? Wkv[(size_t)(j-1024)*1024 + c]
                         : Wp[(size_t)(j-3072)*1024 + c];
    unsigned short h = f2bf(f);
    Whi[w] = h; Wlo[w] = f2bf(f - bf2f(h));
  }
}

// ---------------------------------------------------------------------------
// Templated NT-GEMM core (split bf16, BK=32, 256 threads = 2x2 waves)
// C[m][n] = sum_k A[m][k]*B[n][k]; staging via global_load_lds.
// ---------------------------------------------------------------------------
struct EpiQKV {
  const float* bq; const float* bkv;
  unsigned short *Qhi, *Qlo, *Khi, *Klo, *Vthi, *Vtlo;
  __device__ __forceinline__ void operator()(int m, int n, float v) const {
    if (n < 1024) {                       // Q
      v += bq[n];
      unsigned short h = f2bf(v);
      size_t o = (size_t)m*1024 + n;
      Qhi[o] = h; Qlo[o] = f2bf(v - bf2f(h));
    } else if (n < 2048) {                // K
      v += bkv[n - 1024];
      size_t o = (size_t)m*1024 + (n - 1024);
      unsigned short h = f2bf(v);
      Khi[o] = h; Klo[o] = f2bf(v - bf2f(h));
    } else {                              // V -> transposed [b][h][d][m]
      v += bkv[n - 1024];
      int c = n - 2048;
      int hh = c >> 6, d = c & 63;
      int b = m >> 10, mm = m & 1023;
      size_t o = ((size_t)((b*NH + hh)*HD + d))*SEQ + mm;
      unsigned short h = f2bf(v);
      Vthi[o] = h; Vtlo[o] = f2bf(v - bf2f(h));
    }
  }
};
struct EpiOut {
  const float* bp; float* out;
  __device__ __forceinline__ void operator()(int m, int n, float v) const {
    out[(size_t)m*1024 + n] = v + bp[n];
  }
};

template <int BM, int BN, class Epi>
__device__ __forceinline__ void gemm_core(
    const unsigned short* __restrict__ Ahi, const unsigned short* __restrict__ Alo, int lda,
    const unsigned short* __restrict__ Bhi, const unsigned short* __restrict__ Blo, int ldb,
    int K, const Epi& epi)
{
  constexpr int FM = BM/32, FN = BN/32;     // frags per wave (2x2 wave grid)
  constexpr int CA = BM/16, CB = BN/16;     // 1KB DMA chunks per plane
  constexpr int TOT = 2*(CA+CB);
  __shared__ unsigned short sAh[BM*32], sAl[BM*32], sBh[BN*32], sBl[BN*32];
  const int tid  = threadIdx.x;
  const int lane = tid & 63, wave = tid >> 6;
  const int wm = wave & 1, wn = wave >> 1;
  const int bn = blockIdx.x * BN, bm = blockIdx.y * BM;
  const int r = lane & 15, q = lane >> 4;
  const int crow = lane >> 2, ccol = (lane & 3) * 8;  // chunk: 16 rows x 32 cols

  f32x4 acc[FM][FN];
  #pragma unroll
  for (int i = 0; i < FM; i++)
    #pragma unroll
    for (int j = 0; j < FN; j++) {
      acc[i][j][0]=0.f; acc[i][j][1]=0.f; acc[i][j][2]=0.f; acc[i][j][3]=0.f;
    }

  for (int k0 = 0; k0 < K; k0 += 32) {
    #pragma unroll
    for (int t = 0; t < TOT/4; t++) {
      int c = wave + t*4;
      const unsigned short* gb; unsigned short* sb; int rr, grow, ld;
      if (c < CA)            { gb=Ahi; sb=sAh; rr=c;         grow=bm; ld=lda; }
      else if (c < 2*CA)     { gb=Alo; sb=sAl; rr=c-CA;      grow=bm; ld=lda; }
      else if (c < 2*CA+CB)  { gb=Bhi; sb=sBh; rr=c-2*CA;    grow=bn; ld=ldb; }
      else                   { gb=Blo; sb=sBl; rr=c-2*CA-CB; grow=bn; ld=ldb; }
      int row = rr*16 + crow;
      gl_lds16(gb + (size_t)(grow + row)*ld + k0 + ccol, sb + rr*512);
    }
    __syncthreads();
    bf16x8 ah[FM], al[FM], bh[FN], bl[FN];
    #pragma unroll
    for (int i = 0; i < FM; i++) {
      int oa = (wm*(BM/2) + i*16 + r)*32 + q*8;
      ah[i] = *(const bf16x8*)(sAh + oa);
      al[i] = *(const bf16x8*)(sAl + oa);
    }
    #pragma unroll
    for (int j = 0; j < FN; j++) {
      int ob = (wn*(BN/2) + j*16 + r)*32 + q*8;
      bh[j] = *(const bf16x8*)(sBh + ob);
      bl[j] = *(const bf16x8*)(sBl + ob);
    }
    #pragma unroll
    for (int i = 0; i < FM; i++)
      #pragma unroll
      for (int j = 0; j < FN; j++) {
        acc[i][j] = MFMA16(ah[i], bh[j], acc[i][j]);
        acc[i][j] = MFMA16(ah[i], bl[j], acc[i][j]);
        acc[i][j] = MFMA16(al[i], bh[j], acc[i][j]);
      }
    __syncthreads();
  }
  #pragma unroll
  for (int i = 0; i < FM; i++)
    #pragma unroll
    for (int j = 0; j < FN; j++)
      #pragma unroll
      for (int t = 0; t < 4; t++)
        epi(bm + wm*(BM/2) + i*16 + q*4 + t, bn + wn*(BN/2) + j*16 + r, acc[i][j][t]);
}

__global__ __launch_bounds__(256) void k_gemm_qkv(
    const unsigned short* Xhi, const unsigned short* Xlo,
    const unsigned short* Whi, const unsigned short* Wlo,
    const float* bq, const float* bkv,
    unsigned short* Qhi, unsigned short* Qlo,
    unsigned short* Khi, unsigned short* Klo,
    unsigned short* Vthi, unsigned short* Vtlo)
{
  EpiQKV e{bq, bkv, Qhi, Qlo, Khi, Klo, Vthi, Vtlo};
  gemm_core<128,128>(Xhi, Xlo, CDIM, Whi, Wlo, CDIM, CDIM, e);
}

__global__ __launch_bounds__(256) void k_gemm_out(
    const unsigned short* OAhi, const unsigned short* OAlo,
    const unsigned short* Wphi, const unsigned short* Wplo,
    const float* bp, float* out)
{
  EpiOut e{bp, out};
  gemm_core<64,64>(OAhi, OAlo, CDIM, Wphi, Wplo, CDIM, CDIM, e);
}

// ---------------------------------------------------------------------------
// K2: logits = scale * Q K^T, written DIRECTLY in final attn layout [b][n][m][h].
// wg = (b, 16-n-tile, 32-m-tile), 128 threads, loops 16 heads into LDS slab
// [16n][32m][pad20]; Q/K tiles staged via global_load_lds.
// ---------------------------------------------------------------------------
#define SLAB_PAD 20
__global__ __launch_bounds__(128) void k_logits(
    const unsigned short* __restrict__ Qhi, const unsigned short* __restrict__ Qlo,
    const unsigned short* __restrict__ Khi, const unsigned short* __restrict__ Klo,
    float* __restrict__ attn)
{
  int mt = blockIdx.x, nt = blockIdx.y, b = blockIdx.z;
  int n0 = nt*16, m0 = mt*32;
  __shared__ unsigned short sQh[16*64], sQl[16*64], sKh[32*64], sKl[32*64];
  __shared__ float slab[16*32*SLAB_PAD];
  const int tid = threadIdx.x, lane = tid & 63, wave = tid >> 6;   // 2 waves
  const int r = lane & 15, q = lane >> 4;
  const int crow8 = lane >> 3, ccol8 = (lane & 7) * 8;  // chunk: 8 rows x 64 cols

  for (int h = 0; h < NH; h++) {
    // stage Q (16x64) + K (32x64), hi+lo: 12 1KB chunks over 2 waves
    #pragma unroll
    for (int t = 0; t < 6; t++) {
      int c = wave + t*2;
      const unsigned short* gb; unsigned short* sb; int rr, base;
      if (c < 2)      { gb=Qhi; sb=sQh; rr=c;   base=n0; }
      else if (c < 4) { gb=Qlo; sb=sQl; rr=c-2; base=n0; }
      else if (c < 8) { gb=Khi; sb=sKh; rr=c-4; base=m0; }
      else            { gb=Klo; sb=sKl; rr=c-8; base=m0; }
      int row = rr*8 + crow8;
      gl_lds16(gb + (size_t)(b*SEQ + base + row)*CDIM + h*HD + ccol8, sb + rr*512);
    }
    __syncthreads();
    {
      f32x4 acc; acc[0]=0.f; acc[1]=0.f; acc[2]=0.f; acc[3]=0.f;
      #pragma unroll
      for (int ks = 0; ks < 2; ks++) {
        bf16x8 qh = *(const bf16x8*)(sQh + r*64 + ks*32 + q*8);
        bf16x8 ql = *(const bf16x8*)(sQl + r*64 + ks*32 + q*8);
        bf16x8 kh = *(const bf16x8*)(sKh + (wave*16 + r)*64 + ks*32 + q*8);
        bf16x8 kl = *(const bf16x8*)(sKl + (wave*16 + r)*64 + ks*32 + q*8);
        acc = MFMA16(qh, kh, acc);
        acc = MFMA16(qh, kl, acc);
        acc = MFMA16(ql, kh, acc);
      }
      #pragma unroll
      for (int t = 0; t < 4; t++) {
        int nn = q*4 + t;          // D row = n index
        int mm = wave*16 + r;      // D col = m index
        slab[(nn*32 + mm)*SLAB_PAD + h] = acc[t] * ATT_SCALE;
      }
    }
    __syncthreads();
  }
  // write: 16 n-rows x (32m x 16h) dwords = 2048 float4s
  for (int it = 0; it < 16; it++) {
    int idx = it*128 + tid;
    int nn = idx >> 7;
    int rem = idx & 127;
    int flat = rem * 4;
    int mm = flat >> 4, hh = flat & 15;
    float4 v = *(float4*)&slab[(nn*32 + mm)*SLAB_PAD + hh];
    size_t g = (size_t)(b*SEQ + n0 + nn)*(SEQ*NH) + (size_t)(m0 + mm)*NH + hh;
    *(float4*)(attn + g) = v;
  }
}

// ---------------------------------------------------------------------------
// K3: softmax over m for one (b,n) slab [1024m][16h]; normalized attn f32 in
// place + unnormalized P as u16 fixed point in [b][h][n][m] + scale_pv.
// ---------------------------------------------------------------------------
__global__ __launch_bounds__(256) void k_softmax(
    float* __restrict__ attn, unsigned short* __restrict__ P,
    float* __restrict__ scale_pv)
{
  int n = blockIdx.x, b = blockIdx.y;
  __shared__ float slab[SEQ*NH];
  __shared__ float red[256];
  __shared__ float gmax[16], ginv[16];
  const int tid = threadIdx.x;
  const size_t base = (size_t)(b*SEQ + n) * (SEQ*NH);

  for (int it = 0; it < 16; it++) {
    int f4 = it*256 + tid;
    *(float4*)&slab[f4*4] = *(const float4*)(attn + base + (size_t)f4*4);
  }
  __syncthreads();
  const int h = tid & 15, mq = tid >> 4;
  float mx = -1e30f;
  for (int i = 0; i < 64; i++) mx = fmaxf(mx, slab[(mq*64 + i)*16 + h]);
  red[tid] = mx;
  __syncthreads();
  if (tid < 16) {
    float m2 = red[tid];
    for (int j = 1; j < 16; j++) m2 = fmaxf(m2, red[j*16 + tid]);
    gmax[tid] = m2;
  }
  __syncthreads();
  float gm = gmax[h];
  float s = 0.f;
  for (int i = 0; i < 64; i++) {
    int idx = (mq*64 + i)*16 + h;
    float p = __expf(slab[idx] - gm);
    slab[idx] = p;
    s += p;
  }
  red[tid] = s;
  __syncthreads();
  if (tid < 16) {
    float s2 = 0.f;
    for (int j = 0; j < 16; j++) s2 += red[j*16 + tid];
    float inv = 1.0f / s2;
    ginv[tid] = inv;
    scale_pv[(size_t)(b*SEQ + n)*NH + tid] = inv * (1.0f/65535.0f);
  }
  __syncthreads();
  for (int it = 0; it < 16; it++) {
    int f4 = it*256 + tid;
    int flat = f4*4;
    int hh = flat & 15;
    float4 v = *(float4*)&slab[flat];
    float4 iv = *(float4*)&ginv[hh];
    v.x *= iv.x; v.y *= iv.y; v.z *= iv.z; v.w *= iv.w;
    *(float4*)(attn + base + (size_t)flat) = v;
  }
  int h2 = tid >> 4, l16 = tid & 15;
  size_t pbase = ((size_t)((b*NH + h2)*SEQ + n))*SEQ;
  for (int i = 0; i < 64; i++) {
    int m = i*16 + l16;
    float p = slab[m*16 + h2];
    unsigned int u = (unsigned int)(p * 65535.0f + 0.5f);
    P[pbase + m] = (unsigned short)u;
  }
}

// ---------------------------------------------------------------------------
// K4: PV gemm per (b,h):  OA[n][d] = scale_pv * sum_m P_u16[n][m] * V[m][d]
// 64n x 64d per block (512 blocks), V via global_load_lds, P unpacked exactly
// into two bf16 planes during staging.
// ---------------------------------------------------------------------------
__global__ __launch_bounds__(256) void k_pv(
    const unsigned short* __restrict__ P,
    const unsigned short* __restrict__ Vthi, const unsigned short* __restrict__ Vtlo,
    const float* __restrict__ scale_pv,
    unsigned short* __restrict__ OAhi, unsigned short* __restrict__ OAlo)
{
  int nt = blockIdx.x, h = blockIdx.y, b = blockIdx.z;
  int n0 = nt * 64;
  __shared__ unsigned short sPa[64*32], sPb[64*32], sVh[64*32], sVl[64*32];
  const int tid = threadIdx.x, lane = tid & 63, wave = tid >> 6;
  const int wm = wave & 1, wn = wave >> 1;
  const int r = lane & 15, q = lane >> 4;
  const int crow = lane >> 2, ccol = (lane & 3) * 8;
  const size_t pbase = ((size_t)(b*NH + h))*SEQ*SEQ;
  const size_t vbase = ((size_t)(b*NH + h))*HD*SEQ;

  f32x4 acc[2][2];
  #pragma unroll
  for (int i = 0; i < 2; i++)
    #pragma unroll
    for (int j = 0; j < 2; j++) {
      acc[i][j][0]=0.f; acc[i][j][1]=0.f; acc[i][j][2]=0.f; acc[i][j][3]=0.f;
    }

  for (int k0 = 0; k0 < SEQ; k0 += 32) {
    // V: 2 planes x 4 chunks via DMA; 2 chunks per wave
    #pragma unroll
    for (int t = 0; t < 2; t++) {
      int c = wave + t*4;
      const unsigned short* gb = (c < 4) ? Vthi : Vtlo;
      unsigned short* sb = (c < 4) ? (unsigned short*)sVh : (unsigned short*)sVl;
      int rr = c & 3;
      int row = rr*16 + crow;
      gl_lds16(gb + vbase + (size_t)row*SEQ + k0 + ccol, sb + rr*512);
    }
    // P: 64x32 u16 -> two bf16 planes; one uint4 per thread
    {
      int row = tid >> 2, ch = (tid & 3) * 8;
      uint4 v = *(const uint4*)(P + pbase + (size_t)(n0 + row)*SEQ + k0 + ch);
      unsigned int wds[4] = {v.x, v.y, v.z, v.w};
      unsigned int pa[4], pb[4];
      #pragma unroll
      for (int e = 0; e < 4; e++) {
        unsigned int lo16 = wds[e] & 0xFFFFu;
        unsigned int hi16 = wds[e] >> 16;
        unsigned int a0 = __builtin_bit_cast(uint32_t, (float)(lo16 & 0xFF00u)) >> 16;
        unsigned int b0 = __builtin_bit_cast(uint32_t, (float)(lo16 & 0x00FFu)) >> 16;
        unsigned int a1 = __builtin_bit_cast(uint32_t, (float)(hi16 & 0xFF00u)) >> 16;
        unsigned int b1 = __builtin_bit_cast(uint32_t, (float)(hi16 & 0x00FFu)) >> 16;
        pa[e] = a0 | (a1 << 16);
        pb[e] = b0 | (b1 << 16);
      }
      *(uint4*)(sPa + row*32 + ch) = make_uint4(pa[0],pa[1],pa[2],pa[3]);
      *(uint4*)(sPb + row*32 + ch) = make_uint4(pb[0],pb[1],pb[2],pb[3]);
    }
    __syncthreads();
    bf16x8 pa[2], pb[2], vh[2], vl[2];
    #pragma unroll
    for (int i = 0; i < 2; i++) {
      int off = (wm*32 + i*16 + r)*32 + q*8;
      pa[i] = *(const bf16x8*)(sPa + off);
      pb[i] = *(const bf16x8*)(sPb + off);
    }
    #pragma unroll
    for (int j = 0; j < 2; j++) {
      int off = (wn*32 + j*16 + r)*32 + q*8;
      vh[j] = *(const bf16x8*)(sVh + off);
      vl[j] = *(const bf16x8*)(sVl + off);
    }
    #pragma unroll
    for (int i = 0; i < 2; i++)
      #pragma unroll
      for (int j = 0; j < 2; j++) {
        acc[i][j] = MFMA16(pa[i], vh[j], acc[i][j]);
        acc[i][j] = MFMA16(pb[i], vh[j], acc[i][j]);
        acc[i][j] = MFMA16(pa[i], vl[j], acc[i][j]);
      }
    __syncthreads();
  }
  #pragma unroll
  for (int i = 0; i < 2; i++)
    #pragma unroll
    for (int t = 0; t < 4; t++) {
      int nn = n0 + wm*32 + i*16 + q*4 + t;
      float sc = scale_pv[(size_t)(b*SEQ + nn)*NH + h];
      #pragma unroll
      for (int j = 0; j < 2; j++) {
        int d = wn*32 + j*16 + r;
        float val = acc[i][j][t] * sc;
        size_t o = (size_t)(b*SEQ + nn)*CDIM + h*HD + d;
        unsigned short hb = f2bf(val);
        OAhi[o] = hb; OAlo[o] = f2bf(val - bf2f(hb));
      }
    }
}

// ---------------------------------------------------------------------------
extern "C" void kernel_launch(void* const* d_in, const int* in_sizes, int n_in,
                              void* d_out, int out_size, void* d_ws, size_t ws_size,
                              hipStream_t stream)
{
  const float* x   = (const float*)d_in[0];
  const float* Wq  = (const float*)d_in[1];
  const float* bq  = (const float*)d_in[2];
  const float* Wkv = (const float*)d_in[3];
  const float* bkv = (const float*)d_in[4];
  const float* Wp  = (const float*)d_in[5];
  const float* bp  = (const float*)d_in[6];

  float* out  = (float*)d_out;
  float* attn = out + (size_t)ROWS*CDIM;

  char* w = (char*)d_ws;
  unsigned short* Xhi  = (unsigned short*)w; w += (size_t)ROWS*CDIM*2;
  unsigned short* Xlo  = (unsigned short*)w; w += (size_t)ROWS*CDIM*2;
  unsigned short* Whi  = (unsigned short*)w; w += (size_t)4096*CDIM*2;
  unsigned short* Wlo  = (unsigned short*)w; w += (size_t)4096*CDIM*2;
  unsigned short* Qhi  = (unsigned short*)w; w += (size_t)ROWS*CDIM*2;
  unsigned short* Qlo  = (unsigned short*)w; w += (size_t)ROWS*CDIM*2;
  unsigned short* Khi  = (unsigned short*)w; w += (size_t)ROWS*CDIM*2;
  unsigned short* Klo  = (unsigned short*)w; w += (size_t)ROWS*CDIM*2;
  unsigned short* Vthi = (unsigned short*)w; w += (size_t)NB*NH*HD*SEQ*2;
  unsigned short* Vtlo = (unsigned short*)w; w += (size_t)NB*NH*HD*SEQ*2;
  unsigned short* OAhi = (unsigned short*)w; w += (size_t)ROWS*CDIM*2;
  unsigned short* OAlo = (unsigned short*)w; w += (size_t)ROWS*CDIM*2;
  float* scale_pv      = (float*)w;          w += (size_t)NB*SEQ*NH*4;
  unsigned short* P    = (unsigned short*)w; w += (size_t)NB*NH*SEQ*SEQ*2;

  k_convert<<<dim3((ROWS*CDIM + 4096*CDIM)/256), 256, 0, stream>>>(
      x, Wq, Wkv, Wp, Xhi, Xlo, Whi, Wlo);

  k_gemm_qkv<<<dim3(3072/128, 2048/128), 256, 0, stream>>>(
      Xhi, Xlo, Whi, Wlo, bq, bkv, Qhi, Qlo, Khi, Klo, Vthi, Vtlo);

  k_logits<<<dim3(SEQ/32, SEQ/16, NB), 128, 0, stream>>>(Qhi, Qlo, Khi, Klo, attn);

  k_softmax<<<dim3(SEQ, NB), 256, 0, stream>>>(attn, P, scale_pv);

  k_pv<<<dim3(SEQ/64, NH, NB), 256, 0, stream>>>(P, Vthi, Vtlo, scale_pv, OAhi, OAlo);

  k_gemm_out<<<dim3(1024/64, 2048/64), 256, 0, stream>>>(
      OAhi, OAlo, Whi + (size_t)3072*CDIM, Wlo + (size_t)3072*CDIM, bp, out);
}

// Round 3
// 419.547 us; speedup vs baseline: 1.0832x; 1.0057x over previous
//
#include <hip/hip_runtime.h>
#include <hip/hip_bf16.h>
#include <stdint.h>

// ---------------------------------------------------------------------------
// MultiHeadAttention on MI355X (gfx950).
// b=2, n=1024, DIM=1024, H=16, dh=64.  Outputs: out (2M f32) ++ attn (33.5M f32).
// GEMMs: bf16 MFMA 16x16x32, hi/lo split (3 MFMAs) => ~fp32 accuracy.
// R3: fused logits+softmax -> normalized u16 P (no raw-logit round trip);
//     attn written by a register-transpose dequant kernel (no LDS);
//     K4 scale = 1/65535 constant.
// ---------------------------------------------------------------------------

#define NB   2
#define SEQ  1024
#define CDIM 1024
#define NH   16
#define HD   64
#define ROWS (NB*SEQ)          // 2048
#define ATT_SCALE 0.125f       // 64^-0.5
#define S23  1028              // slab row stride (dwords), == 4 mod 32

typedef __attribute__((ext_vector_type(8))) short bf16x8;
typedef __attribute__((ext_vector_type(4))) float f32x4;

#define MFMA16(a,b,c) __builtin_amdgcn_mfma_f32_16x16x32_bf16((a),(b),(c),0,0,0)

static __device__ __forceinline__ unsigned short f2bf(float f) {
  uint32_t x = __builtin_bit_cast(uint32_t, f);
  return (unsigned short)((x + 0x7fffu + ((x >> 16) & 1u)) >> 16);   // RTN-even
}
static __device__ __forceinline__ float bf2f(unsigned short u) {
  uint32_t x = ((uint32_t)u) << 16;
  return __builtin_bit_cast(float, x);
}

// async global->LDS DMA, 16B/lane; lds dest = wave-uniform base + lane*16
static __device__ __forceinline__ void gl_lds16(const unsigned short* g,
                                                unsigned short* l) {
  __builtin_amdgcn_global_load_lds(
      (const __attribute__((address_space(1))) unsigned int*)g,
      (__attribute__((address_space(3))) unsigned int*)l,
      16, 0, 0);
}

// ---------------------------------------------------------------------------
// K0: fp32 -> bf16 hi/lo split for x and concatenated W = [Wq; Wkv; Wp]
// ---------------------------------------------------------------------------
__global__ __launch_bounds__(256) void k_convert(
    const float* __restrict__ x, const float* __restrict__ Wq,
    const float* __restrict__ Wkv, const float* __restrict__ Wp,
    unsigned short* __restrict__ Xhi, unsigned short* __restrict__ Xlo,
    unsigned short* __restrict__ Whi, unsigned short* __restrict__ Wlo)
{
  const int NX = ROWS * CDIM;
  const int NW = 4096 * CDIM;
  int i = blockIdx.x * 256 + threadIdx.x;
  if (i < NX) {
    float f = x[i];
    unsigned short h = f2bf(f);
    Xhi[i] = h; Xlo[i] = f2bf(f - bf2f(h));
  } else if (i < NX + NW) {
    int w = i - NX;
    int j = w >> 10, c = w & 1023;
    float f = (j < 1024) ? Wq[(size_t)j*1024 + c]
            : (j < 3072) ? Wkv[(size_t)(j-1024)*1024 + c]
                         : Wp[(size_t)(j-3072)*1024 + c];
    unsigned short h = f2bf(f);
    Whi[w] = h; Wlo[w] = f2bf(f - bf2f(h));
  }
}

// ---------------------------------------------------------------------------
// Templated NT-GEMM core (split bf16, BK=32, 256 threads = 2x2 waves)
// ---------------------------------------------------------------------------
struct EpiQKV {
  const float* bq; const float* bkv;
  unsigned short *Qhi, *Qlo, *Khi, *Klo, *Vthi, *Vtlo;
  __device__ __forceinline__ void operator()(int m, int n, float v) const {
    if (n < 1024) {                       // Q
      v += bq[n];
      unsigned short h = f2bf(v);
      size_t o = (size_t)m*1024 + n;
      Qhi[o] = h; Qlo[o] = f2bf(v - bf2f(h));
    } else if (n < 2048) {                // K
      v += bkv[n - 1024];
      size_t o = (size_t)m*1024 + (n - 1024);
      unsigned short h = f2bf(v);
      Khi[o] = h; Klo[o] = f2bf(v - bf2f(h));
    } else {                              // V -> transposed [b][h][d][m]
      v += bkv[n - 1024];
      int c = n - 2048;
      int hh = c >> 6, d = c & 63;
      int b = m >> 10, mm = m & 1023;
      size_t o = ((size_t)((b*NH + hh)*HD + d))*SEQ + mm;
      unsigned short h = f2bf(v);
      Vthi[o] = h; Vtlo[o] = f2bf(v - bf2f(h));
    }
  }
};
struct EpiOut {
  const float* bp; float* out;
  __device__ __forceinline__ void operator()(int m, int n, float v) const {
    out[(size_t)m*1024 + n] = v + bp[n];
  }
};

template <int BM, int BN, class Epi>
__device__ __forceinline__ void gemm_core(
    const unsigned short* __restrict__ Ahi, const unsigned short* __restrict__ Alo, int lda,
    const unsigned short* __restrict__ Bhi, const unsigned short* __restrict__ Blo, int ldb,
    int K, const Epi& epi)
{
  constexpr int FM = BM/32, FN = BN/32;
  constexpr int CA = BM/16, CB = BN/16;
  constexpr int TOT = 2*(CA+CB);
  __shared__ unsigned short sAh[BM*32], sAl[BM*32], sBh[BN*32], sBl[BN*32];
  const int tid  = threadIdx.x;
  const int lane = tid & 63, wave = tid >> 6;
  const int wm = wave & 1, wn = wave >> 1;
  const int bn = blockIdx.x * BN, bm = blockIdx.y * BM;
  const int r = lane & 15, q = lane >> 4;
  const int crow = lane >> 2, ccol = (lane & 3) * 8;

  f32x4 acc[FM][FN];
  #pragma unroll
  for (int i = 0; i < FM; i++)
    #pragma unroll
    for (int j = 0; j < FN; j++) {
      acc[i][j][0]=0.f; acc[i][j][1]=0.f; acc[i][j][2]=0.f; acc[i][j][3]=0.f;
    }

  for (int k0 = 0; k0 < K; k0 += 32) {
    #pragma unroll
    for (int t = 0; t < TOT/4; t++) {
      int c = wave + t*4;
      const unsigned short* gb; unsigned short* sb; int rr, grow, ld;
      if (c < CA)            { gb=Ahi; sb=sAh; rr=c;         grow=bm; ld=lda; }
      else if (c < 2*CA)     { gb=Alo; sb=sAl; rr=c-CA;      grow=bm; ld=lda; }
      else if (c < 2*CA+CB)  { gb=Bhi; sb=sBh; rr=c-2*CA;    grow=bn; ld=ldb; }
      else                   { gb=Blo; sb=sBl; rr=c-2*CA-CB; grow=bn; ld=ldb; }
      int row = rr*16 + crow;
      gl_lds16(gb + (size_t)(grow + row)*ld + k0 + ccol, sb + rr*512);
    }
    __syncthreads();
    bf16x8 ah[FM], al[FM], bh[FN], bl[FN];
    #pragma unroll
    for (int i = 0; i < FM; i++) {
      int oa = (wm*(BM/2) + i*16 + r)*32 + q*8;
      ah[i] = *(const bf16x8*)(sAh + oa);
      al[i] = *(const bf16x8*)(sAl + oa);
    }
    #pragma unroll
    for (int j = 0; j < FN; j++) {
      int ob = (wn*(BN/2) + j*16 + r)*32 + q*8;
      bh[j] = *(const bf16x8*)(sBh + ob);
      bl[j] = *(const bf16x8*)(sBl + ob);
    }
    #pragma unroll
    for (int i = 0; i < FM; i++)
      #pragma unroll
      for (int j = 0; j < FN; j++) {
        acc[i][j] = MFMA16(ah[i], bh[j], acc[i][j]);
        acc[i][j] = MFMA16(ah[i], bl[j], acc[i][j]);
        acc[i][j] = MFMA16(al[i], bh[j], acc[i][j]);
      }
    __syncthreads();
  }
  #pragma unroll
  for (int i = 0; i < FM; i++)
    #pragma unroll
    for (int j = 0; j < FN; j++)
      #pragma unroll
      for (int t = 0; t < 4; t++)
        epi(bm + wm*(BM/2) + i*16 + q*4 + t, bn + wn*(BN/2) + j*16 + r, acc[i][j][t]);
}

__global__ __launch_bounds__(256) void k_gemm_qkv(
    const unsigned short* Xhi, const unsigned short* Xlo,
    const unsigned short* Whi, const unsigned short* Wlo,
    const float* bq, const float* bkv,
    unsigned short* Qhi, unsigned short* Qlo,
    unsigned short* Khi, unsigned short* Klo,
    unsigned short* Vthi, unsigned short* Vtlo)
{
  EpiQKV e{bq, bkv, Qhi, Qlo, Khi, Klo, Vthi, Vtlo};
  gemm_core<128,128>(Xhi, Xlo, CDIM, Whi, Wlo, CDIM, CDIM, e);
}

__global__ __launch_bounds__(256) void k_gemm_out(
    const unsigned short* OAhi, const unsigned short* OAlo,
    const unsigned short* Wphi, const unsigned short* Wplo,
    const float* bp, float* out)
{
  EpiOut e{bp, out};
  gemm_core<64,64>(OAhi, OAlo, CDIM, Wphi, Wplo, CDIM, CDIM, e);
}

// ---------------------------------------------------------------------------
// K23: fused logits + softmax -> normalized u16 P in [b][h][n][m].
// Block = (16 n-rows, 8 heads, b); 256 thr (4 waves). K streamed in 128-m
// DMA chunks (double-buffered, XOR-swizzled LDS). Slab [16n][S23] f32.
// ---------------------------------------------------------------------------
static __device__ __forceinline__ void stage_q23(
    const unsigned short* Qhi, const unsigned short* Qlo,
    size_t qrow0, int col0, unsigned short* sQ,
    int wave, int drow, int dseg)
{
  int p = wave >> 1, t = wave & 1;
  const unsigned short* g = p ? Qlo : Qhi;
  gl_lds16(g + (qrow0 + t*8 + drow)*CDIM + col0 + dseg*8,
           sQ + p*1024 + t*512);
}
static __device__ __forceinline__ void stage_k23(
    const unsigned short* Khi, const unsigned short* Klo,
    size_t krow0, int col0, unsigned short* dstbuf,
    int wave, int drow, int dseg)
{
  #pragma unroll
  for (int u = 0; u < 8; u++) {
    int c = wave*8 + u;
    int p = c >> 4, t = c & 15;
    const unsigned short* g = p ? Klo : Khi;
    gl_lds16(g + (krow0 + t*8 + drow)*CDIM + col0 + dseg*8,
             dstbuf + p*8192 + t*512);
  }
}

__global__ __launch_bounds__(256) void k_logits_softmax(
    const unsigned short* __restrict__ Qhi, const unsigned short* __restrict__ Qlo,
    const unsigned short* __restrict__ Khi, const unsigned short* __restrict__ Klo,
    unsigned short* __restrict__ P)
{
  const int nt = blockIdx.x, hg = blockIdx.y, b = blockIdx.z;
  const int n0 = nt*16;
  __shared__ unsigned short sQ[2*1024];       // [plane][16n x 64k] swizzled
  __shared__ unsigned short sK[2][2*8192];    // [buf][plane][128m x 64k] swizzled
  __shared__ float slab[16*S23];
  __shared__ float red[256];
  __shared__ float gmax[16], gscale[16];
  const int tid = threadIdx.x, lane = tid & 63, wave = tid >> 6;
  const int r = lane & 15, q = lane >> 4;
  const int drow = lane >> 3, dseg = (lane & 7) ^ drow;   // DMA swizzle
  const int sw = r & 7;                                   // read swizzle
  const size_t qrow0 = (size_t)b*SEQ + n0;
  const size_t krow0 = (size_t)b*SEQ;

  {   // initial stage: first head's Q + K chunk 0
    int col0 = (hg*8)*HD;
    stage_q23(Qhi, Qlo, qrow0, col0, sQ, wave, drow, dseg);
    stage_k23(Khi, Klo, krow0, col0, sK[0], wave, drow, dseg);
  }

  for (int hh = 0; hh < 8; hh++) {
    const int h = hg*8 + hh;
    const int col0 = h*HD;
    __syncthreads();          // staged Q/K0 arrived; slab free from prev head
    bf16x8 qh[2], ql[2];
    #pragma unroll
    for (int ks = 0; ks < 2; ks++) {
      int phys = r*64 + (((ks*4 + q) ^ sw))*8;
      qh[ks] = *(const bf16x8*)(sQ + phys);
      ql[ks] = *(const bf16x8*)(sQ + 1024 + phys);
    }
    for (int c128 = 0; c128 < 8; c128++) {
      unsigned short* cur = sK[c128 & 1];
      if (c128 < 7)
        stage_k23(Khi, Klo, krow0 + (size_t)(c128+1)*128, col0,
                  sK[(c128+1)&1], wave, drow, dseg);
      #pragma unroll
      for (int fr = 0; fr < 2; fr++) {
        const int mb = wave*32 + fr*16;
        f32x4 acc; acc[0]=0.f; acc[1]=0.f; acc[2]=0.f; acc[3]=0.f;
        #pragma unroll
        for (int ks = 0; ks < 2; ks++) {
          int phys = (mb + r)*64 + (((ks*4 + q) ^ sw))*8;
          bf16x8 kh = *(const bf16x8*)(cur + phys);
          bf16x8 kl = *(const bf16x8*)(cur + 8192 + phys);
          acc = MFMA16(qh[ks], kh, acc);
          acc = MFMA16(qh[ks], kl, acc);
          acc = MFMA16(ql[ks], kh, acc);
        }
        #pragma unroll
        for (int t = 0; t < 4; t++)
          slab[(q*4+t)*S23 + c128*128 + mb + r] = acc[t] * ATT_SCALE;
      }
      __syncthreads();
    }
    if (hh < 7) {   // prefetch next head's Q + K chunk 0 (overlaps softmax)
      int ncol = (h+1)*HD;
      stage_q23(Qhi, Qlo, qrow0, ncol, sQ, wave, drow, dseg);
      stage_k23(Khi, Klo, krow0, ncol, sK[0], wave, drow, dseg);
    }
    // ---- softmax over m (1024) per row; 16 threads per row
    const int n = tid >> 4, c = tid & 15;
    float mx = -1e30f;
    #pragma unroll 8
    for (int j = 0; j < 64; j++)
      mx = fmaxf(mx, slab[n*S23 + c + j*16]);
    red[tid] = mx;
    __syncthreads();
    if (tid < 16) {
      float m2 = red[tid*16];
      for (int j = 1; j < 16; j++) m2 = fmaxf(m2, red[tid*16 + j]);
      gmax[tid] = m2;
    }
    __syncthreads();
    const float gm = gmax[n];
    float s = 0.f;
    #pragma unroll 8
    for (int j = 0; j < 64; j++) {
      int idx = n*S23 + c + j*16;
      float p = __expf(slab[idx] - gm);
      slab[idx] = p;
      s += p;
    }
    red[tid] = s;
    __syncthreads();
    if (tid < 16) {
      float s2 = 0.f;
      for (int j = 0; j < 16; j++) s2 += red[tid*16 + j];
      gscale[tid] = 65535.0f / s2;
    }
    __syncthreads();
    const float sc = gscale[n];
    const size_t pb = ((size_t)((b*NH + h)*SEQ) + n0 + n)*SEQ;
    #pragma unroll
    for (int j = 0; j < 8; j++) {
      int m0 = (j*16 + c)*8;
      float4 v0 = *(const float4*)&slab[n*S23 + m0];
      float4 v1 = *(const float4*)&slab[n*S23 + m0 + 4];
      unsigned int u0 = (unsigned)(v0.x*sc + 0.5f) | ((unsigned)(v0.y*sc + 0.5f) << 16);
      unsigned int u1 = (unsigned)(v0.z*sc + 0.5f) | ((unsigned)(v0.w*sc + 0.5f) << 16);
      unsigned int u2 = (unsigned)(v1.x*sc + 0.5f) | ((unsigned)(v1.y*sc + 0.5f) << 16);
      unsigned int u3 = (unsigned)(v1.z*sc + 0.5f) | ((unsigned)(v1.w*sc + 0.5f) << 16);
      *(uint4*)(P + pb + m0) = make_uint4(u0, u1, u2, u3);
    }
  }
}

// ---------------------------------------------------------------------------
// K_attn: dequant-transpose P[b][h][n][m] u16 -> attn[b][n][m][h] f32.
// One thread per (b,n,m): 16 coalesced u16 loads, 4 contiguous float4 stores.
// ---------------------------------------------------------------------------
__global__ __launch_bounds__(256) void k_attn_write(
    const unsigned short* __restrict__ P, float* __restrict__ attn)
{
  int T = blockIdx.x*256 + threadIdx.x;
  int b = T >> 20, rem = T & 1048575;
  int n = rem >> 10, m = rem & 1023;
  const size_t pb = ((size_t)(b*NH)*SEQ + n)*SEQ + m;
  float v[16];
  #pragma unroll
  for (int h = 0; h < 16; h++)
    v[h] = (float)P[pb + (size_t)h*SEQ*SEQ] * (1.0f/65535.0f);
  size_t ob = ((size_t)(b*SEQ + n)*SEQ + m)*16;
  #pragma unroll
  for (int g = 0; g < 4; g++)
    *(float4*)(attn + ob + g*4) = make_float4(v[g*4], v[g*4+1], v[g*4+2], v[g*4+3]);
}

// ---------------------------------------------------------------------------
// K4: PV gemm per (b,h):  OA[n][d] = (1/65535) * sum_m P_u16[n][m] * V[m][d]
// 64n x 64d per block (512 blocks); P split exactly into two bf16 planes.
// ---------------------------------------------------------------------------
__global__ __launch_bounds__(256) void k_pv(
    const unsigned short* __restrict__ P,
    const unsigned short* __restrict__ Vthi, const unsigned short* __restrict__ Vtlo,
    unsigned short* __restrict__ OAhi, unsigned short* __restrict__ OAlo)
{
  int nt = blockIdx.x, h = blockIdx.y, b = blockIdx.z;
  int n0 = nt * 64;
  __shared__ unsigned short sPa[64*32], sPb[64*32], sVh[64*32], sVl[64*32];
  const int tid = threadIdx.x, lane = tid & 63, wave = tid >> 6;
  const int wm = wave & 1, wn = wave >> 1;
  const int r = lane & 15, q = lane >> 4;
  const int crow = lane >> 2, ccol = (lane & 3) * 8;
  const size_t pbase = ((size_t)(b*NH + h))*SEQ*SEQ;
  const size_t vbase = ((size_t)(b*NH + h))*HD*SEQ;

  f32x4 acc[2][2];
  #pragma unroll
  for (int i = 0; i < 2; i++)
    #pragma unroll
    for (int j = 0; j < 2; j++) {
      acc[i][j][0]=0.f; acc[i][j][1]=0.f; acc[i][j][2]=0.f; acc[i][j][3]=0.f;
    }

  for (int k0 = 0; k0 < SEQ; k0 += 32) {
    #pragma unroll
    for (int t = 0; t < 2; t++) {
      int c = wave + t*4;
      const unsigned short* gb = (c < 4) ? Vthi : Vtlo;
      unsigned short* sb = (c < 4) ? (unsigned short*)sVh : (unsigned short*)sVl;
      int rr = c & 3;
      int row = rr*16 + crow;
      gl_lds16(gb + vbase + (size_t)row*SEQ + k0 + ccol, sb + rr*512);
    }
    {
      int row = tid >> 2, ch = (tid & 3) * 8;
      uint4 v = *(const uint4*)(P + pbase + (size_t)(n0 + row)*SEQ + k0 + ch);
      unsigned int wds[4] = {v.x, v.y, v.z, v.w};
      unsigned int pa[4], pb4[4];
      #pragma unroll
      for (int e = 0; e < 4; e++) {
        unsigned int lo16 = wds[e] & 0xFFFFu;
        unsigned int hi16 = wds[e] >> 16;
        unsigned int a0 = __builtin_bit_cast(uint32_t, (float)(lo16 & 0xFF00u)) >> 16;
        unsigned int b0 = __builtin_bit_cast(uint32_t, (float)(lo16 & 0x00FFu)) >> 16;
        unsigned int a1 = __builtin_bit_cast(uint32_t, (float)(hi16 & 0xFF00u)) >> 16;
        unsigned int b1 = __builtin_bit_cast(uint32_t, (float)(hi16 & 0x00FFu)) >> 16;
        pa[e]  = a0 | (a1 << 16);
        pb4[e] = b0 | (b1 << 16);
      }
      *(uint4*)(sPa + row*32 + ch) = make_uint4(pa[0],pa[1],pa[2],pa[3]);
      *(uint4*)(sPb + row*32 + ch) = make_uint4(pb4[0],pb4[1],pb4[2],pb4[3]);
    }
    __syncthreads();
    bf16x8 pa[2], pb2[2], vh[2], vl[2];
    #pragma unroll
    for (int i = 0; i < 2; i++) {
      int off = (wm*32 + i*16 + r)*32 + q*8;
      pa[i]  = *(const bf16x8*)(sPa + off);
      pb2[i] = *(const bf16x8*)(sPb + off);
    }
    #pragma unroll
    for (int j = 0; j < 2; j++) {
      int off = (wn*32 + j*16 + r)*32 + q*8;
      vh[j] = *(const bf16x8*)(sVh + off);
      vl[j] = *(const bf16x8*)(sVl + off);
    }
    #pragma unroll
    for (int i = 0; i < 2; i++)
      #pragma unroll
      for (int j = 0; j < 2; j++) {
        acc[i][j] = MFMA16(pa[i],  vh[j], acc[i][j]);
        acc[i][j] = MFMA16(pb2[i], vh[j], acc[i][j]);
        acc[i][j] = MFMA16(pa[i],  vl[j], acc[i][j]);
      }
    __syncthreads();
  }
  #pragma unroll
  for (int i = 0; i < 2; i++)
    #pragma unroll
    for (int t = 0; t < 4; t++) {
      int nn = n0 + wm*32 + i*16 + q*4 + t;
      #pragma unroll
      for (int j = 0; j < 2; j++) {
        int d = wn*32 + j*16 + r;
        float val = acc[i][j][t] * (1.0f/65535.0f);
        size_t o = (size_t)(b*SEQ + nn)*CDIM + h*HD + d;
        unsigned short hb = f2bf(val);
        OAhi[o] = hb; OAlo[o] = f2bf(val - bf2f(hb));
      }
    }
}

// ---------------------------------------------------------------------------
extern "C" void kernel_launch(void* const* d_in, const int* in_sizes, int n_in,
                              void* d_out, int out_size, void* d_ws, size_t ws_size,
                              hipStream_t stream)
{
  const float* x   = (const float*)d_in[0];
  const float* Wq  = (const float*)d_in[1];
  const float* bq  = (const float*)d_in[2];
  const float* Wkv = (const float*)d_in[3];
  const float* bkv = (const float*)d_in[4];
  const float* Wp  = (const float*)d_in[5];
  const float* bp  = (const float*)d_in[6];

  float* out  = (float*)d_out;
  float* attn = out + (size_t)ROWS*CDIM;

  char* w = (char*)d_ws;
  unsigned short* Xhi  = (unsigned short*)w; w += (size_t)ROWS*CDIM*2;
  unsigned short* Xlo  = (unsigned short*)w; w += (size_t)ROWS*CDIM*2;
  unsigned short* Whi  = (unsigned short*)w; w += (size_t)4096*CDIM*2;
  unsigned short* Wlo  = (unsigned short*)w; w += (size_t)4096*CDIM*2;
  unsigned short* Qhi  = (unsigned short*)w; w += (size_t)ROWS*CDIM*2;
  unsigned short* Qlo  = (unsigned short*)w; w += (size_t)ROWS*CDIM*2;
  unsigned short* Khi  = (unsigned short*)w; w += (size_t)ROWS*CDIM*2;
  unsigned short* Klo  = (unsigned short*)w; w += (size_t)ROWS*CDIM*2;
  unsigned short* Vthi = (unsigned short*)w; w += (size_t)NB*NH*HD*SEQ*2;
  unsigned short* Vtlo = (unsigned short*)w; w += (size_t)NB*NH*HD*SEQ*2;
  unsigned short* OAhi = (unsigned short*)w; w += (size_t)ROWS*CDIM*2;
  unsigned short* OAlo = (unsigned short*)w; w += (size_t)ROWS*CDIM*2;
  unsigned short* P    = (unsigned short*)w; w += (size_t)NB*NH*SEQ*SEQ*2;

  k_convert<<<dim3((ROWS*CDIM + 4096*CDIM)/256), 256, 0, stream>>>(
      x, Wq, Wkv, Wp, Xhi, Xlo, Whi, Wlo);

  k_gemm_qkv<<<dim3(3072/128, 2048/128), 256, 0, stream>>>(
      Xhi, Xlo, Whi, Wlo, bq, bkv, Qhi, Qlo, Khi, Klo, Vthi, Vtlo);

  k_logits_softmax<<<dim3(SEQ/16, 2, NB), 256, 0, stream>>>(
      Qhi, Qlo, Khi, Klo, P);

  k_pv<<<dim3(SEQ/64, NH, NB), 256, 0, stream>>>(P, Vthi, Vtlo, OAhi, OAlo);

  k_gemm_out<<<dim3(1024/64, 2048/64), 256, 0, stream>>>(
      OAhi, OAlo, Whi + (size_t)3072*CDIM, Wlo + (size_t)3072*CDIM, bp, out);

  k_attn_write<<<dim3((NB*SEQ*SEQ)/256), 256, 0, stream>>>(P, attn);
}